// Round 1
// baseline (368.946 us; speedup 1.0000x reference)
//
#include <hip/hip_runtime.h>
#include <math.h>

#define NB 4096
#define NC 128
#define NK 32
#define NE 128

__device__ __forceinline__ float sigmoidf_(float x){
  if (x >= 0.f){ float z = expf(-x); return 1.f/(1.f+z); }
  float z = expf(x); return z/(1.f+z);
}
__device__ __forceinline__ float softplusf_(float x){
  // matches jax.nn.softplus = max(x,0) + log1p(exp(-|x|))
  return fmaxf(x, 0.f) + log1pf(expf(-fabsf(x)));
}

// ---------------- transpose small weights for coalesced access ----------------
__global__ void k_prep(const float* __restrict__ fp_w1, const float* __restrict__ ps_w1,
                       float* __restrict__ w1at, float* __restrict__ w1bt,
                       float* __restrict__ ps_w1t){
  int idx = blockIdx.x*256 + threadIdx.x;
  if (idx < 128*128){
    int o = idx >> 7, e = idx & 127;
    w1at[e*128 + o] = fp_w1[o*258 + e];
    w1bt[e*128 + o] = fp_w1[o*258 + 128 + e];
  } else {
    int i2 = idx - 128*128;
    if (i2 < 128*32){
      int e = i2 >> 5, q = i2 & 31;
      ps_w1t[e*32 + q] = ps_w1[q*128 + e];
    }
  }
}

// ---------------- stable counting-sort grouping (matches jnp.argsort) ----------------
__global__ void k_group(const int* __restrict__ assign, int* __restrict__ g,
                        int* __restrict__ row_of){
  __shared__ int hist[NC];
  __shared__ int loc[256];
  int t = threadIdx.x;
  int start = blockIdx.x*256;
  for (int c = t; c < NC; c += 256) hist[c] = 0;
  __syncthreads();
  for (int j = t; j < start; j += 256) atomicAdd(&hist[assign[j]], 1);
  int i = start + t;
  int c = assign[i];
  loc[t] = c;
  __syncthreads();
  int r = hist[c];
  for (int j = 0; j < 256; ++j) r += (j < t && loc[j] == c) ? 1 : 0;
  if (r >= NK) r = NK - 1;   // safety (input guarantees exactly 32/cluster)
  g[c*NK + r] = i;
  row_of[i] = c*NK + r;
}

// ---------------- per-building: prio MLP, net, pos (clustered layout) ----------------
__global__ void k_prio(const float* __restrict__ emb, const float* __restrict__ gen,
                       const float* __restrict__ cons, const float* __restrict__ pos,
                       const float* __restrict__ ps_w1t, const float* __restrict__ ps_b1,
                       const float* __restrict__ ps_w2, const float* __restrict__ ps_b2,
                       const int* __restrict__ row_of, const int* __restrict__ hourp,
                       float* __restrict__ net_c, float* __restrict__ prio_c,
                       float* __restrict__ pos_c){
  __shared__ float es[8*128];
  int t = threadIdx.x;
  int i0 = blockIdx.x*8;
  for (int idx = t; idx < 8*128; idx += 256) es[idx] = emb[i0*128 + idx];
  __syncthreads();
  int bl = t >> 5, q = t & 31;
  int i = i0 + bl;
  float acc = ps_b1[q];
  const float* er = &es[bl*128];
  for (int e = 0; e < 128; ++e) acc = fmaf(er[e], ps_w1t[e*32 + q], acc);
  float v = fmaxf(acc, 0.f) * ps_w2[q];
  for (int m = 16; m >= 1; m >>= 1) v += __shfl_xor(v, m, 32);
  if (q == 0){
    int ck = row_of[i];
    prio_c[ck] = sigmoidf_(v + ps_b2[0]);
    int h = hourp[0];
    net_c[ck] = gen[i*24 + h] - cons[i*24 + h];
    pos_c[2*ck]   = pos[2*i];
    pos_c[2*ck+1] = pos[2*i+1];
  }
}

// ---------------- hi/hj = emb @ W1a.T / W1b.T (clustered layout) ----------------
__global__ void k_hij(const float* __restrict__ emb, const float* __restrict__ w1at,
                      const float* __restrict__ w1bt, const int* __restrict__ row_of,
                      float* __restrict__ hi_c, float* __restrict__ hj_c){
  __shared__ float es[16*132];
  int t = threadIdx.x;
  int i0 = blockIdx.x*16;
  for (int idx = t; idx < 16*128; idx += 256){
    int b = idx >> 7, e = idx & 127;
    es[b*132 + e] = emb[(i0 + b)*128 + e];
  }
  __syncthreads();
  int o = t & 127, half = t >> 7;
  float ai[8], aj[8];
#pragma unroll
  for (int r = 0; r < 8; ++r){ ai[r] = 0.f; aj[r] = 0.f; }
  for (int e = 0; e < 128; e += 4){
    float wa0 = w1at[(e+0)*128 + o], wa1 = w1at[(e+1)*128 + o];
    float wa2 = w1at[(e+2)*128 + o], wa3 = w1at[(e+3)*128 + o];
    float wb0 = w1bt[(e+0)*128 + o], wb1 = w1bt[(e+1)*128 + o];
    float wb2 = w1bt[(e+2)*128 + o], wb3 = w1bt[(e+3)*128 + o];
#pragma unroll
    for (int r = 0; r < 8; ++r){
      float4 ev = *(const float4*)&es[(half*8 + r)*132 + e];
      ai[r] = fmaf(ev.x, wa0, fmaf(ev.y, wa1, fmaf(ev.z, wa2, fmaf(ev.w, wa3, ai[r]))));
      aj[r] = fmaf(ev.x, wb0, fmaf(ev.y, wb1, fmaf(ev.z, wb2, fmaf(ev.w, wb3, aj[r]))));
    }
  }
#pragma unroll
  for (int r = 0; r < 8; ++r){
    int b = i0 + half*8 + r;
    int ck = row_of[b];
    hi_c[ck*128 + o] = ai[r];
    hj_c[ck*128 + o] = aj[r];
  }
}

// ---------------- pairwise dist + efficiency MLP (1->16->1) ----------------
__global__ void k_eff(const float* __restrict__ pos_c, const float* __restrict__ en_w1,
                      const float* __restrict__ en_b1, const float* __restrict__ en_w2,
                      const float* __restrict__ en_b2,
                      float* __restrict__ dist, float* __restrict__ eff){
  int idx = blockIdx.x*256 + threadIdx.x;          // [0, 131072)
  int j = idx & 31, tmp = idx >> 5, i = tmp & 31, c = tmp >> 5;
  float xi = pos_c[(c*NK + i)*2 + 0], yi = pos_c[(c*NK + i)*2 + 1];
  float xj = pos_c[(c*NK + j)*2 + 0], yj = pos_c[(c*NK + j)*2 + 1];
  float dx = xi - xj, dy = yi - yj;
  float d = sqrtf(dx*dx + dy*dy);
  float ds = d / 1000.0f;
  float accv = en_b2[0];
#pragma unroll
  for (int q = 0; q < 16; ++q){
    float ehq = fmaxf(ds*en_w1[q] + en_b1[q], 0.f);
    accv = fmaf(ehq, en_w2[q], accv);
  }
  dist[idx] = d;
  eff[idx] = 0.85f + 0.13f*sigmoidf_(accv);
}

// ---------------- pflow MLP: h1(128) -> h2(64) -> softplus, per (c,i) tile ----------------
__global__ __launch_bounds__(128) void k_pflow(
    const float* __restrict__ hi_c, const float* __restrict__ hj_c,
    const float* __restrict__ dist, const float* __restrict__ fp_w1,
    const float* __restrict__ fp_b1, const float* __restrict__ fp_w2,
    const float* __restrict__ fp_b2, const float* __restrict__ fp_w3,
    const float* __restrict__ fp_b3, const int* __restrict__ hourp,
    float* __restrict__ pflow){
  __shared__ float w2s[64*132];   // padded rows: stride 132 keeps <=2-way bank aliasing
  __shared__ float h1s[32*132];
  __shared__ float dl[32];
  __shared__ float w3s[64];
  __shared__ float b2s[64];
  int t = threadIdx.x;
  int blk = blockIdx.x;
  int c = blk >> 5, i = blk & 31;
  int ci = c*NK + i;
  for (int idx = t; idx < 64*128; idx += 128)
    w2s[(idx >> 7)*132 + (idx & 127)] = fp_w2[idx];
  if (t < 64){ w3s[t] = fp_w3[t]; b2s[t] = fp_b2[t]; }
  if (t < 32) dl[t] = dist[c*1024 + i*32 + t];
  float hour_f = (float)hourp[0] / 24.0f;
  float w1d = fp_w1[t*258 + 256];
  float w1h = fp_w1[t*258 + 257];
  float bz = hi_c[ci*128 + t] + hour_f*w1h + fp_b1[t];
  __syncthreads();
  for (int k = 0; k < 32; ++k){
    float hv = hj_c[(c*NK + k)*128 + t];
    h1s[k*132 + t] = fmaxf(bz + hv + dl[k]*w1d, 0.f);
  }
  __syncthreads();
  int jb = t >> 4, ob = t & 15;       // j in {jb, jb+8, jb+16, jb+24}; o in {ob, ob+16, ob+32, ob+48}
  float acc[4][4];
#pragma unroll
  for (int r = 0; r < 4; ++r)
#pragma unroll
    for (int s = 0; s < 4; ++s) acc[r][s] = 0.f;
  for (int z = 0; z < 128; z += 4){
    float4 hv4[4], wv4[4];
#pragma unroll
    for (int r = 0; r < 4; ++r) hv4[r] = *(const float4*)&h1s[(jb + 8*r)*132 + z];
#pragma unroll
    for (int s = 0; s < 4; ++s) wv4[s] = *(const float4*)&w2s[(ob + 16*s)*132 + z];
#pragma unroll
    for (int r = 0; r < 4; ++r)
#pragma unroll
      for (int s = 0; s < 4; ++s){
        acc[r][s] = fmaf(hv4[r].x, wv4[s].x, acc[r][s]);
        acc[r][s] = fmaf(hv4[r].y, wv4[s].y, acc[r][s]);
        acc[r][s] = fmaf(hv4[r].z, wv4[s].z, acc[r][s]);
        acc[r][s] = fmaf(hv4[r].w, wv4[s].w, acc[r][s]);
      }
  }
  float b3 = fp_b3[0];
#pragma unroll
  for (int r = 0; r < 4; ++r){
    float pacc = 0.f;
#pragma unroll
    for (int s = 0; s < 4; ++s){
      int o = ob + 16*s;
      float h2 = fmaxf(acc[r][s] + b2s[o], 0.f);
      pacc = fmaf(h2, w3s[o], pacc);
    }
    for (int m = 8; m >= 1; m >>= 1) pacc += __shfl_xor(pacc, m, 16);
    if (ob == 0) pflow[c*1024 + i*32 + (jb + 8*r)] = softplusf_(pacc + b3);
  }
}

// ---------------- fill sharing=0, effmat=1, total=0 ----------------
__global__ void k_fill(float4* __restrict__ sharing4, float4* __restrict__ effm4,
                       float* __restrict__ total){
  unsigned idx = blockIdx.x*256u + threadIdx.x;
  float4 z4 = make_float4(0.f, 0.f, 0.f, 0.f);
  float4 o4 = make_float4(1.f, 1.f, 1.f, 1.f);
  for (unsigned p = idx; p < 4194304u; p += gridDim.x*256u){
    sharing4[p] = z4;
    effm4[p] = o4;
  }
  if (idx == 0) total[0] = 0.f;
}

// ---------------- greedy allocation per cluster (exact sequential replication) ----------------
__global__ __launch_bounds__(64) void k_greedy(
    const float* __restrict__ net_c, const float* __restrict__ prio_c,
    const float* __restrict__ eff, const float* __restrict__ pflow,
    const int* __restrict__ g,
    float* __restrict__ sharing, float* __restrict__ effm, float* __restrict__ total,
    float* __restrict__ esent, float* __restrict__ erecv, float* __restrict__ nafter){
  __shared__ int order_s[32];
  __shared__ int gl[32];
  __shared__ float fl_un[32*33];
  __shared__ float ef_un[32*33];
  int t = threadIdx.x;
  int c = blockIdx.x;
  float p = (t < 32) ? prio_c[c*NK + t] : -1e30f;
  if (t < 32) gl[t] = g[c*NK + t];
  // stable descending argsort of prio (ties by original index) — rank of lane t
  int rank = 0;
  for (int k = 0; k < 32; ++k){
    float pk = __shfl(p, k);
    rank += ((pk > p) || (pk == p && k < t)) ? 1 : 0;
  }
  if (t < 32) order_s[rank] = t;
  __syncthreads();
  int b = (t < 32) ? order_s[t] : 0;                 // original index of ordered slot t
  float net0 = (t < 32) ? net_c[c*NK + b] : 0.f;     // net_o (original, constant)
  float dnet = net0;
  float recv = 0.f;
  float ctotal = 0.f;
  for (int i = 0; i < 32; ++i){
    int a = __shfl(b, i);                            // original index of ordered sender i
    float pf = pflow[c*1024 + a*32 + b];
    float ef = eff[c*1024 + a*32 + b];
    if (t >= 32){ pf = 0.f; ef = 1.f; }
    float avail = fmaxf(__shfl(net0, i), 0.f);
    float flow = 0.f;
    int act = 0;
    for (int jj = 0; jj < 32; ++jj){
      float needed = -dnet;
      int a_c = (avail > 0.f) && (needed > 0.f);
      float f_c = a_c ? fminf(fminf(avail, needed), pf) : 0.f;
      float f_b = __shfl(f_c, jj);
      if (t == jj){ flow = f_c; act = a_c; dnet = dnet + f_c*ef; }
      avail -= f_b;
    }
    if (t < 32){
      fl_un[a*33 + b] = flow;
      ef_un[a*33 + b] = act ? ef : 1.0f;
    }
    recv = fmaf(flow, ef, recv);
    float rs = flow;
    for (int m = 16; m >= 1; m >>= 1) rs += __shfl_xor(rs, m, 32);
    if (t == 0){ esent[gl[a]] = rs; ctotal += rs; }
  }
  __syncthreads();
  if (t < 32){
    nafter[gl[b]] = dnet;
    erecv[gl[b]] = recv;
  }
  if (t == 0) atomicAdd(total, ctotal);
  // scatter the K x K cluster block into the N x N outputs
  for (int e = t; e < 1024; e += 64){
    int aa = e >> 5, bb = e & 31;
    long row = gl[aa], col = gl[bb];
    sharing[row*(long)NB + col] = fl_un[aa*33 + bb];
    effm[row*(long)NB + col]    = ef_un[aa*33 + bb];
  }
}

extern "C" void kernel_launch(void* const* d_in, const int* in_sizes, int n_in,
                              void* d_out, int out_size, void* d_ws, size_t ws_size,
                              hipStream_t stream){
  (void)in_sizes; (void)n_in; (void)out_size; (void)ws_size;
  const float* emb   = (const float*)d_in[0];
  const float* gen   = (const float*)d_in[1];
  const float* cons  = (const float*)d_in[2];
  const float* pos   = (const float*)d_in[3];
  const float* fp_w1 = (const float*)d_in[4];
  const float* fp_b1 = (const float*)d_in[5];
  const float* fp_w2 = (const float*)d_in[6];
  const float* fp_b2 = (const float*)d_in[7];
  const float* fp_w3 = (const float*)d_in[8];
  const float* fp_b3 = (const float*)d_in[9];
  const float* en_w1 = (const float*)d_in[10];
  const float* en_b1 = (const float*)d_in[11];
  const float* en_w2 = (const float*)d_in[12];
  const float* en_b2 = (const float*)d_in[13];
  const float* ps_w1 = (const float*)d_in[14];
  const float* ps_b1 = (const float*)d_in[15];
  const float* ps_w2 = (const float*)d_in[16];
  const float* ps_b2 = (const float*)d_in[17];
  const int*   assign = (const int*)d_in[18];
  const int*   hourp  = (const int*)d_in[20];

  char* ws = (char*)d_ws;
  float* w1at   = (float*)(ws + 0);
  float* w1bt   = (float*)(ws + 65536);
  float* ps_w1t = (float*)(ws + 131072);
  int*   g      = (int*)  (ws + 147456);
  int*   row_of = (int*)  (ws + 163840);
  float* net_c  = (float*)(ws + 180224);
  float* prio_c = (float*)(ws + 196608);
  float* pos_c  = (float*)(ws + 212992);
  float* hi_c   = (float*)(ws + 245760);
  float* hj_c   = (float*)(ws + 2342912);
  float* dist   = (float*)(ws + 4440064);
  float* eff    = (float*)(ws + 4964352);
  float* pflow  = (float*)(ws + 5488640);

  float* sharing = (float*)d_out;
  float* effm    = sharing + (long)NB*NB;
  float* total   = effm + (long)NB*NB;
  float* esent   = total + 1;
  float* erecv   = esent + NB;
  float* nafter  = erecv + NB;

  hipLaunchKernelGGL(k_fill, dim3(4096), dim3(256), 0, stream,
                     (float4*)sharing, (float4*)effm, total);
  hipLaunchKernelGGL(k_prep, dim3(80), dim3(256), 0, stream,
                     fp_w1, ps_w1, w1at, w1bt, ps_w1t);
  hipLaunchKernelGGL(k_group, dim3(16), dim3(256), 0, stream,
                     assign, g, row_of);
  hipLaunchKernelGGL(k_prio, dim3(512), dim3(256), 0, stream,
                     emb, gen, cons, pos, ps_w1t, ps_b1, ps_w2, ps_b2,
                     row_of, hourp, net_c, prio_c, pos_c);
  hipLaunchKernelGGL(k_hij, dim3(256), dim3(256), 0, stream,
                     emb, w1at, w1bt, row_of, hi_c, hj_c);
  hipLaunchKernelGGL(k_eff, dim3(512), dim3(256), 0, stream,
                     pos_c, en_w1, en_b1, en_w2, en_b2, dist, eff);
  hipLaunchKernelGGL(k_pflow, dim3(4096), dim3(128), 0, stream,
                     hi_c, hj_c, dist, fp_w1, fp_b1, fp_w2, fp_b2, fp_w3, fp_b3,
                     hourp, pflow);
  hipLaunchKernelGGL(k_greedy, dim3(128), dim3(64), 0, stream,
                     net_c, prio_c, eff, pflow, g,
                     sharing, effm, total, esent, erecv, nafter);
}

// Round 2
// 327.264 us; speedup vs baseline: 1.1274x; 1.1274x over previous
//
#include <hip/hip_runtime.h>
#include <math.h>

#define NB 4096
#define NC 128
#define NK 32
#define NE 128

__device__ __forceinline__ float sigmoidf_(float x){
  if (x >= 0.f){ float z = expf(-x); return 1.f/(1.f+z); }
  float z = expf(x); return z/(1.f+z);
}
__device__ __forceinline__ float softplusf_(float x){
  // matches jax.nn.softplus = max(x,0) + log1p(exp(-|x|))
  return fmaxf(x, 0.f) + log1pf(expf(-fabsf(x)));
}

// ---------------- prep (transposes + fused-const precompute) + grouping + total=0 ----------------
// blocks 0..79: weight transposes; 80..95: counting-sort grouping; 96: w1d/bz consts + total=0
__global__ void k_prep_group(const float* __restrict__ fp_w1, const float* __restrict__ ps_w1,
                             const float* __restrict__ fp_b1, const int* __restrict__ assign,
                             const int* __restrict__ hourp,
                             float* __restrict__ w1at, float* __restrict__ w1bt,
                             float* __restrict__ ps_w1t, int* __restrict__ g,
                             int* __restrict__ row_of, float* __restrict__ w1d_c,
                             float* __restrict__ bzc, float* __restrict__ total){
  int bid = blockIdx.x;
  int t = threadIdx.x;
  if (bid < 80){
    int idx = bid*256 + t;
    if (idx < 128*128){
      int o = idx >> 7, e = idx & 127;
      w1at[e*128 + o] = fp_w1[o*258 + e];
      w1bt[e*128 + o] = fp_w1[o*258 + 128 + e];
    } else {
      int i2 = idx - 128*128;
      if (i2 < 128*32){
        int e = i2 >> 5, q = i2 & 31;
        ps_w1t[e*32 + q] = ps_w1[q*128 + e];
      }
    }
  } else if (bid < 96){
    __shared__ int hist[NC];
    __shared__ int loc[256];
    int start = (bid - 80)*256;
    for (int c = t; c < NC; c += 256) hist[c] = 0;
    __syncthreads();
    for (int j = t; j < start; j += 256) atomicAdd(&hist[assign[j]], 1);
    int i = start + t;
    int c = assign[i];
    loc[t] = c;
    __syncthreads();
    int r = hist[c];
    for (int j = 0; j < 256; ++j) r += (j < t && loc[j] == c) ? 1 : 0;
    if (r >= NK) r = NK - 1;
    g[c*NK + r] = i;
    row_of[i] = c*NK + r;
  } else {
    if (t < 128){
      float hour_f = (float)hourp[0] / 24.0f;
      w1d_c[t] = fp_w1[t*258 + 256];
      bzc[t]   = fmaf(hour_f, fp_w1[t*258 + 257], fp_b1[t]);
    }
    if (t == 128) total[0] = 0.f;
  }
}

// ---------------- per-building: prio MLP, net, pos (clustered layout) ----------------
__global__ void k_prio(const float* __restrict__ emb, const float* __restrict__ gen,
                       const float* __restrict__ cons, const float* __restrict__ pos,
                       const float* __restrict__ ps_w1t, const float* __restrict__ ps_b1,
                       const float* __restrict__ ps_w2, const float* __restrict__ ps_b2,
                       const int* __restrict__ row_of, const int* __restrict__ hourp,
                       float* __restrict__ net_c, float* __restrict__ prio_c,
                       float* __restrict__ pos_c){
  __shared__ float es[8*128];
  __shared__ float ws[128*32];
  int t = threadIdx.x;
  int i0 = blockIdx.x*8;
  for (int idx = t; idx < 8*128; idx += 256) es[idx] = emb[i0*128 + idx];
  for (int idx = t; idx < 128*32; idx += 256) ws[idx] = ps_w1t[idx];
  __syncthreads();
  int bl = t >> 5, q = t & 31;
  int i = i0 + bl;
  float acc = ps_b1[q];
  const float* er = &es[bl*128];
  for (int e = 0; e < 128; ++e) acc = fmaf(er[e], ws[e*32 + q], acc);
  float v = fmaxf(acc, 0.f) * ps_w2[q];
  for (int m = 16; m >= 1; m >>= 1) v += __shfl_xor(v, m, 32);
  if (q == 0){
    int ck = row_of[i];
    prio_c[ck] = sigmoidf_(v + ps_b2[0]);
    int h = hourp[0];
    net_c[ck] = gen[i*24 + h] - cons[i*24 + h];
    pos_c[2*ck]   = pos[2*i];
    pos_c[2*ck+1] = pos[2*i+1];
  }
}

// ---------------- hi/hj = emb @ W1a.T / W1b.T (clustered layout) ----------------
__global__ void k_hij(const float* __restrict__ emb, const float* __restrict__ w1at,
                      const float* __restrict__ w1bt, const int* __restrict__ row_of,
                      float* __restrict__ hi_c, float* __restrict__ hj_c){
  __shared__ float es[16*132];
  int t = threadIdx.x;
  int i0 = blockIdx.x*16;
  for (int idx = t; idx < 16*128; idx += 256){
    int b = idx >> 7, e = idx & 127;
    es[b*132 + e] = emb[(i0 + b)*128 + e];
  }
  __syncthreads();
  int o = t & 127, half = t >> 7;
  float ai[8], aj[8];
#pragma unroll
  for (int r = 0; r < 8; ++r){ ai[r] = 0.f; aj[r] = 0.f; }
  for (int e = 0; e < 128; e += 4){
    float wa0 = w1at[(e+0)*128 + o], wa1 = w1at[(e+1)*128 + o];
    float wa2 = w1at[(e+2)*128 + o], wa3 = w1at[(e+3)*128 + o];
    float wb0 = w1bt[(e+0)*128 + o], wb1 = w1bt[(e+1)*128 + o];
    float wb2 = w1bt[(e+2)*128 + o], wb3 = w1bt[(e+3)*128 + o];
#pragma unroll
    for (int r = 0; r < 8; ++r){
      float4 ev = *(const float4*)&es[(half*8 + r)*132 + e];
      ai[r] = fmaf(ev.x, wa0, fmaf(ev.y, wa1, fmaf(ev.z, wa2, fmaf(ev.w, wa3, ai[r]))));
      aj[r] = fmaf(ev.x, wb0, fmaf(ev.y, wb1, fmaf(ev.z, wb2, fmaf(ev.w, wb3, aj[r]))));
    }
  }
#pragma unroll
  for (int r = 0; r < 8; ++r){
    int b = i0 + half*8 + r;
    int ck = row_of[b];
    hi_c[ck*128 + o] = ai[r];
    hj_c[ck*128 + o] = aj[r];
  }
}

// ---------------- pflow MLP: one (i,j) pair per lane; W2 via wave-uniform scalar loads ----------------
// h1 row (128 f32) lives in VGPRs; W2/W3/b2 rows are wave-uniform -> s_load (SMEM pipe).
// Pure VALU-bound: 2.15 GFLOP total.
__global__ __launch_bounds__(64) void k_pflow(
    const float* __restrict__ hi_c, const float* __restrict__ hj_c,
    const float* __restrict__ pos_c, const float* __restrict__ w1d_c,
    const float* __restrict__ bzc, const float* __restrict__ fp_w2,
    const float* __restrict__ fp_b2, const float* __restrict__ fp_w3,
    const float* __restrict__ fp_b3, float* __restrict__ pflow){
  int t = threadIdx.x;
  int blk = blockIdx.x;
  int c = blk >> 4, ip = blk & 15;
  int i = ip*2 + (t >> 5);
  int j = t & 31;
  // distance for this (i,j)
  float xi = pos_c[(c*NK + i)*2 + 0], yi = pos_c[(c*NK + i)*2 + 1];
  float xj = pos_c[(c*NK + j)*2 + 0], yj = pos_c[(c*NK + j)*2 + 1];
  float dx = xi - xj, dy = yi - yj;
  float d = sqrtf(fmaf(dx, dx, dy*dy));
  // build h1 row in registers
  const float4* hi4 = (const float4*)(hi_c + (c*NK + i)*128);
  const float4* hj4 = (const float4*)(hj_c + (c*NK + j)*128);
  const float4* wd4 = (const float4*)w1d_c;
  const float4* bz4 = (const float4*)bzc;
  float h1r[128];
#pragma unroll
  for (int z4 = 0; z4 < 32; ++z4){
    float4 a = hi4[z4], b = hj4[z4], w = wd4[z4], bb = bz4[z4];
    h1r[z4*4+0] = fmaxf(a.x + b.x + fmaf(d, w.x, bb.x), 0.f);
    h1r[z4*4+1] = fmaxf(a.y + b.y + fmaf(d, w.y, bb.y), 0.f);
    h1r[z4*4+2] = fmaxf(a.z + b.z + fmaf(d, w.z, bb.z), 0.f);
    h1r[z4*4+3] = fmaxf(a.w + b.w + fmaf(d, w.w, bb.w), 0.f);
  }
  float b3 = fp_b3[0];
  float pacc = 0.f;
  for (int o = 0; o < 64; ++o){
    const float* w2r = fp_w2 + o*128;     // wave-uniform -> scalar loads
    float a0 = 0.f, a1 = 0.f, a2 = 0.f, a3 = 0.f;
#pragma unroll
    for (int z = 0; z < 128; z += 4){
      a0 = fmaf(h1r[z+0], w2r[z+0], a0);
      a1 = fmaf(h1r[z+1], w2r[z+1], a1);
      a2 = fmaf(h1r[z+2], w2r[z+2], a2);
      a3 = fmaf(h1r[z+3], w2r[z+3], a3);
    }
    float h2 = fmaxf((a0 + a1) + (a2 + a3) + fp_b2[o], 0.f);
    pacc = fmaf(h2, fp_w3[o], pacc);
  }
  pflow[c*1024 + i*32 + j] = softplusf_(pacc + b3);
}

// ---------------- greedy allocation: prefix-scan form, eff computed inline ----------------
__global__ __launch_bounds__(64) void k_greedy(
    const float* __restrict__ net_c, const float* __restrict__ prio_c,
    const float* __restrict__ pos_c, const float* __restrict__ en_w1,
    const float* __restrict__ en_b1, const float* __restrict__ en_w2,
    const float* __restrict__ en_b2, const float* __restrict__ pflow,
    const int* __restrict__ g,
    float* __restrict__ fl_c, float* __restrict__ ef_c, float* __restrict__ total,
    float* __restrict__ esent, float* __restrict__ erecv, float* __restrict__ nafter){
  __shared__ float pf_s[1024];
  __shared__ float ef_s[1024];
  __shared__ float fl_s[1024];
  __shared__ float efm_s[1024];
  __shared__ float px[32], py[32];
  __shared__ int order_s[32];
  __shared__ int gl[32];
  int t = threadIdx.x;
  int tl = t & 31;
  int c = blockIdx.x;
  for (int e = t; e < 1024; e += 64) pf_s[e] = pflow[c*1024 + e];
  if (t < 32){
    float2 p2 = ((const float2*)pos_c)[c*NK + t];
    px[t] = p2.x; py[t] = p2.y;
    gl[t] = g[c*NK + t];
  }
  __syncthreads();
  // efficiency tile (1->16->1 MLP on dist)
  for (int e = t; e < 1024; e += 64){
    int ii = e >> 5, jj = e & 31;
    float dx = px[ii] - px[jj], dy = py[ii] - py[jj];
    float d = sqrtf(fmaf(dx, dx, dy*dy));
    float ds = d * (1.0f/1000.0f);
    float acc = en_b2[0];
#pragma unroll
    for (int q = 0; q < 16; ++q)
      acc = fmaf(fmaxf(fmaf(ds, en_w1[q], en_b1[q]), 0.f), en_w2[q], acc);
    ef_s[e] = 0.85f + 0.13f*sigmoidf_(acc);
  }
  // stable descending argsort of prio (ties by original index)
  float p = (t < 32) ? prio_c[c*NK + t] : -1e30f;
  int rank = 0;
  for (int k = 0; k < 32; ++k){
    float pk = __shfl(p, k, 32);
    rank += ((pk > p) || (pk == p && k < tl)) ? 1 : 0;
  }
  if (t < 32) order_s[rank] = t;
  __syncthreads();
  int b = order_s[tl];                       // original index of ordered receiver slot tl
  float net0 = net_c[c*NK + b];
  float dnet = net0;
  float recv = 0.f;
  float ctotal = 0.f;
  for (int i = 0; i < 32; ++i){
    int a = order_s[i];                      // original index of ordered sender i
    float av0 = fmaxf(__shfl(net0, i, 32), 0.f);
    float pf = pf_s[a*32 + b];
    float ef = ef_s[a*32 + b];
    float needed = -dnet;
    float m = (needed > 0.f) ? fminf(needed, pf) : 0.f;
    // inclusive prefix sum of m over the 32 ordered receivers
    float s = m;
#pragma unroll
    for (int dd = 1; dd < 32; dd <<= 1){
      float u = __shfl_up(s, dd, 32);
      if (tl >= dd) s += u;
    }
    float Se = __shfl_up(s, 1, 32);
    if (tl == 0) Se = 0.f;
    float rprev = fmaxf(av0 - Se, 0.f);      // remaining surplus before this slot
    int act = (rprev > 0.f) && (needed > 0.f);
    float f = fminf(m, rprev);
    dnet = fmaf(f, ef, dnet);
    recv = fmaf(f, ef, recv);
    if (t < 32){
      fl_s[a*32 + b]  = f;
      efm_s[a*32 + b] = act ? ef : 1.0f;
    }
    float rs = f;
    for (int mm = 16; mm >= 1; mm >>= 1) rs += __shfl_xor(rs, mm, 32);
    if (t == 0){ esent[gl[a]] = rs; ctotal += rs; }
  }
  if (t < 32){
    nafter[gl[b]] = dnet;
    erecv[gl[b]]  = recv;
  }
  if (t == 0) atomicAdd(total, ctotal);
  __syncthreads();
  for (int e = t; e < 1024; e += 64){
    fl_c[c*1024 + e] = fl_s[e];
    ef_c[c*1024 + e] = efm_s[e];
  }
}

// ---------------- stream N x N outputs: build each row in LDS, write once ----------------
__global__ __launch_bounds__(256) void k_write(
    const float* __restrict__ fl_c, const float* __restrict__ ef_c,
    const int* __restrict__ g, const int* __restrict__ row_of,
    float* __restrict__ sharing, float* __restrict__ effm){
  __shared__ float rowS[4096];
  __shared__ float rowE[4096];
  __shared__ int   cols[32];
  __shared__ float vals[32];
  __shared__ float vale[32];
  int t = threadIdx.x;
  int r = blockIdx.x;
  int ra = row_of[r];
  int c = ra >> 5, a = ra & 31;
  if (t < 32){
    cols[t] = g[c*NK + t];
    vals[t] = fl_c[c*1024 + a*32 + t];
    vale[t] = ef_c[c*1024 + a*32 + t];
  }
  float4 z4 = make_float4(0.f, 0.f, 0.f, 0.f);
  float4 o4 = make_float4(1.f, 1.f, 1.f, 1.f);
  float4* s4 = (float4*)rowS;
  float4* e4 = (float4*)rowE;
#pragma unroll
  for (int q = 0; q < 4; ++q){ s4[t + 256*q] = z4; e4[t + 256*q] = o4; }
  __syncthreads();
  if (t < 32){ rowS[cols[t]] = vals[t]; rowE[cols[t]] = vale[t]; }
  __syncthreads();
  float4* gs = (float4*)(sharing + (long)r*NB);
  float4* ge = (float4*)(effm    + (long)r*NB);
#pragma unroll
  for (int q = 0; q < 4; ++q){ gs[t + 256*q] = s4[t + 256*q]; ge[t + 256*q] = e4[t + 256*q]; }
}

extern "C" void kernel_launch(void* const* d_in, const int* in_sizes, int n_in,
                              void* d_out, int out_size, void* d_ws, size_t ws_size,
                              hipStream_t stream){
  (void)in_sizes; (void)n_in; (void)out_size; (void)ws_size;
  const float* emb   = (const float*)d_in[0];
  const float* gen   = (const float*)d_in[1];
  const float* cons  = (const float*)d_in[2];
  const float* pos   = (const float*)d_in[3];
  const float* fp_w1 = (const float*)d_in[4];
  const float* fp_b1 = (const float*)d_in[5];
  const float* fp_w2 = (const float*)d_in[6];
  const float* fp_b2 = (const float*)d_in[7];
  const float* fp_w3 = (const float*)d_in[8];
  const float* fp_b3 = (const float*)d_in[9];
  const float* en_w1 = (const float*)d_in[10];
  const float* en_b1 = (const float*)d_in[11];
  const float* en_w2 = (const float*)d_in[12];
  const float* en_b2 = (const float*)d_in[13];
  const float* ps_w1 = (const float*)d_in[14];
  const float* ps_b1 = (const float*)d_in[15];
  const float* ps_w2 = (const float*)d_in[16];
  const float* ps_b2 = (const float*)d_in[17];
  const int*   assign = (const int*)d_in[18];
  const int*   hourp  = (const int*)d_in[20];

  char* ws = (char*)d_ws;
  float* w1at   = (float*)(ws + 0);          // 64 KB
  float* w1bt   = (float*)(ws + 65536);      // 64 KB
  float* ps_w1t = (float*)(ws + 131072);     // 16 KB
  int*   g      = (int*)  (ws + 147456);     // 16 KB
  int*   row_of = (int*)  (ws + 163840);     // 16 KB
  float* net_c  = (float*)(ws + 180224);     // 16 KB
  float* prio_c = (float*)(ws + 196608);     // 16 KB
  float* pos_c  = (float*)(ws + 212992);     // 32 KB
  float* w1d_c  = (float*)(ws + 245760);     // 512 B
  float* bzc    = (float*)(ws + 246272);     // 512 B
  float* hi_c   = (float*)(ws + 262144);     // 2 MB
  float* hj_c   = (float*)(ws + 2359296);    // 2 MB
  float* pflow  = (float*)(ws + 4456448);    // 512 KB
  float* fl_c   = (float*)(ws + 4980736);    // 512 KB
  float* ef_c   = (float*)(ws + 5505024);    // 512 KB

  float* sharing = (float*)d_out;
  float* effm    = sharing + (long)NB*NB;
  float* total   = effm + (long)NB*NB;
  float* esent   = total + 1;
  float* erecv   = esent + NB;
  float* nafter  = erecv + NB;

  hipLaunchKernelGGL(k_prep_group, dim3(97), dim3(256), 0, stream,
                     fp_w1, ps_w1, fp_b1, assign, hourp,
                     w1at, w1bt, ps_w1t, g, row_of, w1d_c, bzc, total);
  hipLaunchKernelGGL(k_prio, dim3(512), dim3(256), 0, stream,
                     emb, gen, cons, pos, ps_w1t, ps_b1, ps_w2, ps_b2,
                     row_of, hourp, net_c, prio_c, pos_c);
  hipLaunchKernelGGL(k_hij, dim3(256), dim3(256), 0, stream,
                     emb, w1at, w1bt, row_of, hi_c, hj_c);
  hipLaunchKernelGGL(k_pflow, dim3(2048), dim3(64), 0, stream,
                     hi_c, hj_c, pos_c, w1d_c, bzc, fp_w2, fp_b2, fp_w3, fp_b3,
                     pflow);
  hipLaunchKernelGGL(k_greedy, dim3(128), dim3(64), 0, stream,
                     net_c, prio_c, pos_c, en_w1, en_b1, en_w2, en_b2, pflow, g,
                     fl_c, ef_c, total, esent, erecv, nafter);
  hipLaunchKernelGGL(k_write, dim3(4096), dim3(256), 0, stream,
                     fl_c, ef_c, g, row_of, sharing, effm);
}

// Round 3
// 274.320 us; speedup vs baseline: 1.3449x; 1.1930x over previous
//
#include <hip/hip_runtime.h>
#include <math.h>

#define NB 4096
#define NC 128
#define NK 32
#define NE 128

typedef __bf16 bf16x8 __attribute__((ext_vector_type(8)));
typedef float floatx4 __attribute__((ext_vector_type(4)));

__device__ __forceinline__ float sigmoidf_(float x){
  if (x >= 0.f){ float z = expf(-x); return 1.f/(1.f+z); }
  float z = expf(x); return z/(1.f+z);
}
__device__ __forceinline__ float softplusf_(float x){
  // matches jax.nn.softplus = max(x,0) + log1p(exp(-|x|))
  return fmaxf(x, 0.f) + log1pf(expf(-fabsf(x)));
}
__device__ __forceinline__ unsigned int pack_bf16(float a, float b){
  unsigned short ua = __builtin_bit_cast(unsigned short, (__bf16)a);
  unsigned short ub = __builtin_bit_cast(unsigned short, (__bf16)b);
  return (unsigned int)ua | ((unsigned int)ub << 16);
}

// ---------------- prep (transposes + consts + W2 bf16 pack) + grouping + total=0 ----------------
// blocks 0..79: weight transposes; 80..95: counting-sort grouping; 96: consts; 97: W2 bf16 pack
__global__ void k_prep_group(const float* __restrict__ fp_w1, const float* __restrict__ ps_w1,
                             const float* __restrict__ fp_b1, const float* __restrict__ fp_w2,
                             const int* __restrict__ assign, const int* __restrict__ hourp,
                             float* __restrict__ w1at, float* __restrict__ w1bt,
                             float* __restrict__ ps_w1t, int* __restrict__ g,
                             int* __restrict__ row_of, float* __restrict__ w1d_c,
                             float* __restrict__ bzc, unsigned int* __restrict__ w2b,
                             float* __restrict__ total){
  int bid = blockIdx.x;
  int t = threadIdx.x;
  if (bid < 80){
    int idx = bid*256 + t;
    if (idx < 128*128){
      int o = idx >> 7, e = idx & 127;
      w1at[e*128 + o] = fp_w1[o*258 + e];
      w1bt[e*128 + o] = fp_w1[o*258 + 128 + e];
    } else {
      int i2 = idx - 128*128;
      if (i2 < 128*32){
        int e = i2 >> 5, q = i2 & 31;
        ps_w1t[e*32 + q] = ps_w1[q*128 + e];
      }
    }
  } else if (bid < 96){
    __shared__ int hist[NC];
    __shared__ int loc[256];
    int start = (bid - 80)*256;
    for (int c = t; c < NC; c += 256) hist[c] = 0;
    __syncthreads();
    for (int j = t; j < start; j += 256) atomicAdd(&hist[assign[j]], 1);
    int i = start + t;
    int c = assign[i];
    loc[t] = c;
    __syncthreads();
    int r = hist[c];
    for (int j = 0; j < 256; ++j) r += (j < t && loc[j] == c) ? 1 : 0;
    if (r >= NK) r = NK - 1;
    g[c*NK + r] = i;
    row_of[i] = c*NK + r;
  } else if (bid == 96){
    if (t < 128){
      float hour_f = (float)hourp[0] / 24.0f;
      w1d_c[t] = fp_w1[t*258 + 256];
      bzc[t]   = fmaf(hour_f, fp_w1[t*258 + 257], fp_b1[t]);
    }
    if (t == 128) total[0] = 0.f;
  } else {
    // pack fp_w2 [64][128] f32 -> [64][64] uint (2x bf16)
    for (int idx = t; idx < 4096; idx += 256)
      w2b[idx] = pack_bf16(fp_w2[2*idx], fp_w2[2*idx + 1]);
  }
}

// ---------------- per-building: prio MLP, net, pos (clustered layout) ----------------
__global__ void k_prio(const float* __restrict__ emb, const float* __restrict__ gen,
                       const float* __restrict__ cons, const float* __restrict__ pos,
                       const float* __restrict__ ps_w1t, const float* __restrict__ ps_b1,
                       const float* __restrict__ ps_w2, const float* __restrict__ ps_b2,
                       const int* __restrict__ row_of, const int* __restrict__ hourp,
                       float* __restrict__ net_c, float* __restrict__ prio_c,
                       float* __restrict__ pos_c){
  __shared__ float es[8*128];
  __shared__ float ws[128*32];
  int t = threadIdx.x;
  int i0 = blockIdx.x*8;
  for (int idx = t; idx < 8*128; idx += 256) es[idx] = emb[i0*128 + idx];
  for (int idx = t; idx < 128*32; idx += 256) ws[idx] = ps_w1t[idx];
  __syncthreads();
  int bl = t >> 5, q = t & 31;
  int i = i0 + bl;
  float acc = ps_b1[q];
  const float* er = &es[bl*128];
  for (int e = 0; e < 128; ++e) acc = fmaf(er[e], ws[e*32 + q], acc);
  float v = fmaxf(acc, 0.f) * ps_w2[q];
  for (int m = 16; m >= 1; m >>= 1) v += __shfl_xor(v, m, 32);
  if (q == 0){
    int ck = row_of[i];
    prio_c[ck] = sigmoidf_(v + ps_b2[0]);
    int h = hourp[0];
    net_c[ck] = gen[i*24 + h] - cons[i*24 + h];
    pos_c[2*ck]   = pos[2*i];
    pos_c[2*ck+1] = pos[2*i+1];
  }
}

// ---------------- hi/hj = emb @ W1a.T / W1b.T (clustered layout) ----------------
__global__ void k_hij(const float* __restrict__ emb, const float* __restrict__ w1at,
                      const float* __restrict__ w1bt, const int* __restrict__ row_of,
                      float* __restrict__ hi_c, float* __restrict__ hj_c){
  __shared__ float es[16*132];
  int t = threadIdx.x;
  int i0 = blockIdx.x*16;
  for (int idx = t; idx < 16*128; idx += 256){
    int b = idx >> 7, e = idx & 127;
    es[b*132 + e] = emb[(i0 + b)*128 + e];
  }
  __syncthreads();
  int o = t & 127, half = t >> 7;
  float ai[8], aj[8];
#pragma unroll
  for (int r = 0; r < 8; ++r){ ai[r] = 0.f; aj[r] = 0.f; }
  for (int e = 0; e < 128; e += 4){
    float wa0 = w1at[(e+0)*128 + o], wa1 = w1at[(e+1)*128 + o];
    float wa2 = w1at[(e+2)*128 + o], wa3 = w1at[(e+3)*128 + o];
    float wb0 = w1bt[(e+0)*128 + o], wb1 = w1bt[(e+1)*128 + o];
    float wb2 = w1bt[(e+2)*128 + o], wb3 = w1bt[(e+3)*128 + o];
#pragma unroll
    for (int r = 0; r < 8; ++r){
      float4 ev = *(const float4*)&es[(half*8 + r)*132 + e];
      ai[r] = fmaf(ev.x, wa0, fmaf(ev.y, wa1, fmaf(ev.z, wa2, fmaf(ev.w, wa3, ai[r]))));
      aj[r] = fmaf(ev.x, wb0, fmaf(ev.y, wb1, fmaf(ev.z, wb2, fmaf(ev.w, wb3, aj[r]))));
    }
  }
#pragma unroll
  for (int r = 0; r < 8; ++r){
    int b = i0 + half*8 + r;
    int ck = row_of[b];
    hi_c[ck*128 + o] = ai[r];
    hj_c[ck*128 + o] = aj[r];
  }
}

// ---------------- pflow MLP via MFMA bf16: [128 pairs x 128] @ [128 x 64] per block ----------------
// block = (cluster c, 4 sender rows). h1 built in f32, stored packed-bf16 in LDS
// (row stride 68 dwords -> 2-way bank aliasing = free). W2 pre-packed bf16.
__global__ __launch_bounds__(256) void k_pflow(
    const float* __restrict__ hi_c, const float* __restrict__ hj_c,
    const float* __restrict__ pos_c, const float* __restrict__ w1d_c,
    const float* __restrict__ bzc, const unsigned int* __restrict__ w2b,
    const float* __restrict__ fp_b2, const float* __restrict__ fp_w3,
    const float* __restrict__ fp_b3, float* __restrict__ pflow){
  __shared__ unsigned int h1s[128*68];   // 128 pairs x 128 bf16 (stride 68 dwords)
  __shared__ unsigned int w2s[64*68];    // 64 o x 128 bf16
  int t = threadIdx.x;
  int blk = blockIdx.x;
  int c = blk >> 3, iblk = blk & 7;
  int i0 = iblk*4;
  // stage W2
  for (int idx = t; idx < 4096; idx += 256)
    w2s[(idx >> 6)*68 + (idx & 63)] = w2b[idx];
  // build h1: thread t -> pair p = t>>1, k-half h = t&1 (64 k's)
  {
    int p = t >> 1, h = t & 1;
    int i = i0 + (p >> 5), j = p & 31;
    float xi = pos_c[(c*NK + i)*2 + 0], yi = pos_c[(c*NK + i)*2 + 1];
    float xj = pos_c[(c*NK + j)*2 + 0], yj = pos_c[(c*NK + j)*2 + 1];
    float dx = xi - xj, dy = yi - yj;
    float d = sqrtf(fmaf(dx, dx, dy*dy));
    const float4* hi4 = (const float4*)(hi_c + (c*NK + i)*128) + h*16;
    const float4* hj4 = (const float4*)(hj_c + (c*NK + j)*128) + h*16;
    const float4* wd4 = (const float4*)w1d_c + h*16;
    const float4* bz4 = (const float4*)bzc + h*16;
    unsigned int* dst = &h1s[p*68 + h*32];
#pragma unroll
    for (int z = 0; z < 16; ++z){
      float4 a = hi4[z], b = hj4[z], w = wd4[z], bb = bz4[z];
      float v0 = fmaxf(a.x + b.x + fmaf(d, w.x, bb.x), 0.f);
      float v1 = fmaxf(a.y + b.y + fmaf(d, w.y, bb.y), 0.f);
      float v2 = fmaxf(a.z + b.z + fmaf(d, w.z, bb.z), 0.f);
      float v3 = fmaxf(a.w + b.w + fmaf(d, w.w, bb.w), 0.f);
      dst[2*z]     = pack_bf16(v0, v1);
      dst[2*z + 1] = pack_bf16(v2, v3);
    }
  }
  __syncthreads();
  // MFMA phase: M=128 N=64 K=128; wave w handles m-tiles {2w, 2w+1}
  int lane = t & 63, wv = t >> 6;
  int quad = lane >> 4, l16 = lane & 15;
  // B fragments (all 4 n-tiles x 4 k-steps) hoisted to registers
  bf16x8 bfr[4][4];
#pragma unroll
  for (int nt = 0; nt < 4; ++nt)
#pragma unroll
    for (int ks = 0; ks < 4; ++ks){
      int o = nt*16 + l16;
      bfr[nt][ks] = *(const bf16x8*)((const char*)w2s + o*272 + ks*64 + quad*16);
    }
  float b3 = fp_b3[0];
  float b2v[4], w3v[4];
#pragma unroll
  for (int nt = 0; nt < 4; ++nt){
    b2v[nt] = fp_b2[nt*16 + l16];
    w3v[nt] = fp_w3[nt*16 + l16];
  }
  int idx0 = c*1024 + i0*32;
#pragma unroll
  for (int mt2 = 0; mt2 < 2; ++mt2){
    int mt = wv*2 + mt2;
    bf16x8 af[4];
#pragma unroll
    for (int ks = 0; ks < 4; ++ks){
      int m = mt*16 + l16;
      af[ks] = *(const bf16x8*)((const char*)h1s + m*272 + ks*64 + quad*16);
    }
    floatx4 acc[4];
#pragma unroll
    for (int nt = 0; nt < 4; ++nt){
      acc[nt] = (floatx4){0.f, 0.f, 0.f, 0.f};
#pragma unroll
      for (int ks = 0; ks < 4; ++ks)
        acc[nt] = __builtin_amdgcn_mfma_f32_16x16x32_bf16(af[ks], bfr[nt][ks], acc[nt], 0, 0, 0);
    }
    // epilogue: h2 = relu(acc + b2), pacc = h2 . w3, reduce over o (16 lanes)
    float s0 = 0.f, s1 = 0.f, s2 = 0.f, s3 = 0.f;
#pragma unroll
    for (int nt = 0; nt < 4; ++nt){
      s0 = fmaf(fmaxf(acc[nt][0] + b2v[nt], 0.f), w3v[nt], s0);
      s1 = fmaf(fmaxf(acc[nt][1] + b2v[nt], 0.f), w3v[nt], s1);
      s2 = fmaf(fmaxf(acc[nt][2] + b2v[nt], 0.f), w3v[nt], s2);
      s3 = fmaf(fmaxf(acc[nt][3] + b2v[nt], 0.f), w3v[nt], s3);
    }
#pragma unroll
    for (int m = 8; m >= 1; m >>= 1){
      s0 += __shfl_xor(s0, m);
      s1 += __shfl_xor(s1, m);
      s2 += __shfl_xor(s2, m);
      s3 += __shfl_xor(s3, m);
    }
    if (l16 == 0){
      int base = idx0 + mt*16 + quad*4;
      pflow[base + 0] = softplusf_(s0 + b3);
      pflow[base + 1] = softplusf_(s1 + b3);
      pflow[base + 2] = softplusf_(s2 + b3);
      pflow[base + 3] = softplusf_(s3 + b3);
    }
  }
}

// ---------------- greedy allocation: prefix-scan form, eff computed inline ----------------
__global__ __launch_bounds__(64) void k_greedy(
    const float* __restrict__ net_c, const float* __restrict__ prio_c,
    const float* __restrict__ pos_c, const float* __restrict__ en_w1,
    const float* __restrict__ en_b1, const float* __restrict__ en_w2,
    const float* __restrict__ en_b2, const float* __restrict__ pflow,
    const int* __restrict__ g,
    float* __restrict__ fl_c, float* __restrict__ ef_c, float* __restrict__ total,
    float* __restrict__ esent, float* __restrict__ erecv, float* __restrict__ nafter){
  __shared__ float pf_s[1024];
  __shared__ float ef_s[1024];
  __shared__ float fl_s[1024];
  __shared__ float efm_s[1024];
  __shared__ float px[32], py[32];
  __shared__ int order_s[32];
  __shared__ int gl[32];
  int t = threadIdx.x;
  int tl = t & 31;
  int c = blockIdx.x;
  for (int e = t; e < 1024; e += 64) pf_s[e] = pflow[c*1024 + e];
  if (t < 32){
    float2 p2 = ((const float2*)pos_c)[c*NK + t];
    px[t] = p2.x; py[t] = p2.y;
    gl[t] = g[c*NK + t];
  }
  __syncthreads();
  // efficiency tile (1->16->1 MLP on dist)
  for (int e = t; e < 1024; e += 64){
    int ii = e >> 5, jj = e & 31;
    float dx = px[ii] - px[jj], dy = py[ii] - py[jj];
    float d = sqrtf(fmaf(dx, dx, dy*dy));
    float ds = d * (1.0f/1000.0f);
    float acc = en_b2[0];
#pragma unroll
    for (int q = 0; q < 16; ++q)
      acc = fmaf(fmaxf(fmaf(ds, en_w1[q], en_b1[q]), 0.f), en_w2[q], acc);
    ef_s[e] = 0.85f + 0.13f*sigmoidf_(acc);
  }
  // stable descending argsort of prio (ties by original index)
  float p = (t < 32) ? prio_c[c*NK + t] : -1e30f;
  int rank = 0;
  for (int k = 0; k < 32; ++k){
    float pk = __shfl(p, k, 32);
    rank += ((pk > p) || (pk == p && k < tl)) ? 1 : 0;
  }
  if (t < 32) order_s[rank] = t;
  __syncthreads();
  int b = order_s[tl];                       // original index of ordered receiver slot tl
  float net0 = net_c[c*NK + b];
  float dnet = net0;
  float recv = 0.f;
  float ctotal = 0.f;
  for (int i = 0; i < 32; ++i){
    int a = order_s[i];                      // original index of ordered sender i
    float av0 = fmaxf(__shfl(net0, i, 32), 0.f);
    float pf = pf_s[a*32 + b];
    float ef = ef_s[a*32 + b];
    float needed = -dnet;
    float m = (needed > 0.f) ? fminf(needed, pf) : 0.f;
    // inclusive prefix sum of m over the 32 ordered receivers
    float s = m;
#pragma unroll
    for (int dd = 1; dd < 32; dd <<= 1){
      float u = __shfl_up(s, dd, 32);
      if (tl >= dd) s += u;
    }
    float Se = __shfl_up(s, 1, 32);
    if (tl == 0) Se = 0.f;
    float rprev = fmaxf(av0 - Se, 0.f);      // remaining surplus before this slot
    int act = (rprev > 0.f) && (needed > 0.f);
    float f = fminf(m, rprev);
    dnet = fmaf(f, ef, dnet);
    recv = fmaf(f, ef, recv);
    if (t < 32){
      fl_s[a*32 + b]  = f;
      efm_s[a*32 + b] = act ? ef : 1.0f;
    }
    float rs = f;
    for (int mm = 16; mm >= 1; mm >>= 1) rs += __shfl_xor(rs, mm, 32);
    if (t == 0){ esent[gl[a]] = rs; ctotal += rs; }
  }
  if (t < 32){
    nafter[gl[b]] = dnet;
    erecv[gl[b]]  = recv;
  }
  if (t == 0) atomicAdd(total, ctotal);
  __syncthreads();
  for (int e = t; e < 1024; e += 64){
    fl_c[c*1024 + e] = fl_s[e];
    ef_c[c*1024 + e] = efm_s[e];
  }
}

// ---------------- stream N x N outputs: build each row in LDS, write once ----------------
__global__ __launch_bounds__(256) void k_write(
    const float* __restrict__ fl_c, const float* __restrict__ ef_c,
    const int* __restrict__ g, const int* __restrict__ row_of,
    float* __restrict__ sharing, float* __restrict__ effm){
  __shared__ float rowS[4096];
  __shared__ float rowE[4096];
  __shared__ int   cols[32];
  __shared__ float vals[32];
  __shared__ float vale[32];
  int t = threadIdx.x;
  int r = blockIdx.x;
  int ra = row_of[r];
  int c = ra >> 5, a = ra & 31;
  if (t < 32){
    cols[t] = g[c*NK + t];
    vals[t] = fl_c[c*1024 + a*32 + t];
    vale[t] = ef_c[c*1024 + a*32 + t];
  }
  float4 z4 = make_float4(0.f, 0.f, 0.f, 0.f);
  float4 o4 = make_float4(1.f, 1.f, 1.f, 1.f);
  float4* s4 = (float4*)rowS;
  float4* e4 = (float4*)rowE;
#pragma unroll
  for (int q = 0; q < 4; ++q){ s4[t + 256*q] = z4; e4[t + 256*q] = o4; }
  __syncthreads();
  if (t < 32){ rowS[cols[t]] = vals[t]; rowE[cols[t]] = vale[t]; }
  __syncthreads();
  float4* gs = (float4*)(sharing + (long)r*NB);
  float4* ge = (float4*)(effm    + (long)r*NB);
#pragma unroll
  for (int q = 0; q < 4; ++q){ gs[t + 256*q] = s4[t + 256*q]; ge[t + 256*q] = e4[t + 256*q]; }
}

extern "C" void kernel_launch(void* const* d_in, const int* in_sizes, int n_in,
                              void* d_out, int out_size, void* d_ws, size_t ws_size,
                              hipStream_t stream){
  (void)in_sizes; (void)n_in; (void)out_size; (void)ws_size;
  const float* emb   = (const float*)d_in[0];
  const float* gen   = (const float*)d_in[1];
  const float* cons  = (const float*)d_in[2];
  const float* pos   = (const float*)d_in[3];
  const float* fp_w1 = (const float*)d_in[4];
  const float* fp_b1 = (const float*)d_in[5];
  const float* fp_w2 = (const float*)d_in[6];
  const float* fp_b2 = (const float*)d_in[7];
  const float* fp_w3 = (const float*)d_in[8];
  const float* fp_b3 = (const float*)d_in[9];
  const float* en_w1 = (const float*)d_in[10];
  const float* en_b1 = (const float*)d_in[11];
  const float* en_w2 = (const float*)d_in[12];
  const float* en_b2 = (const float*)d_in[13];
  const float* ps_w1 = (const float*)d_in[14];
  const float* ps_b1 = (const float*)d_in[15];
  const float* ps_w2 = (const float*)d_in[16];
  const float* ps_b2 = (const float*)d_in[17];
  const int*   assign = (const int*)d_in[18];
  const int*   hourp  = (const int*)d_in[20];

  char* ws = (char*)d_ws;
  float* w1at   = (float*)(ws + 0);          // 64 KB
  float* w1bt   = (float*)(ws + 65536);      // 64 KB
  float* ps_w1t = (float*)(ws + 131072);     // 16 KB
  int*   g      = (int*)  (ws + 147456);     // 16 KB
  int*   row_of = (int*)  (ws + 163840);     // 16 KB
  float* net_c  = (float*)(ws + 180224);     // 16 KB
  float* prio_c = (float*)(ws + 196608);     // 16 KB
  float* pos_c  = (float*)(ws + 212992);     // 32 KB
  float* w1d_c  = (float*)(ws + 245760);     // 512 B
  float* bzc    = (float*)(ws + 246272);     // 512 B
  float* hi_c   = (float*)(ws + 262144);     // 2 MB
  float* hj_c   = (float*)(ws + 2359296);    // 2 MB
  float* pflow  = (float*)(ws + 4456448);    // 512 KB
  float* fl_c   = (float*)(ws + 4980736);    // 512 KB
  float* ef_c   = (float*)(ws + 5505024);    // 512 KB
  unsigned int* w2b = (unsigned int*)(ws + 6029312); // 16 KB

  float* sharing = (float*)d_out;
  float* effm    = sharing + (long)NB*NB;
  float* total   = effm + (long)NB*NB;
  float* esent   = total + 1;
  float* erecv   = esent + NB;
  float* nafter  = erecv + NB;

  hipLaunchKernelGGL(k_prep_group, dim3(98), dim3(256), 0, stream,
                     fp_w1, ps_w1, fp_b1, fp_w2, assign, hourp,
                     w1at, w1bt, ps_w1t, g, row_of, w1d_c, bzc, w2b, total);
  hipLaunchKernelGGL(k_prio, dim3(512), dim3(256), 0, stream,
                     emb, gen, cons, pos, ps_w1t, ps_b1, ps_w2, ps_b2,
                     row_of, hourp, net_c, prio_c, pos_c);
  hipLaunchKernelGGL(k_hij, dim3(256), dim3(256), 0, stream,
                     emb, w1at, w1bt, row_of, hi_c, hj_c);
  hipLaunchKernelGGL(k_pflow, dim3(1024), dim3(256), 0, stream,
                     hi_c, hj_c, pos_c, w1d_c, bzc, w2b, fp_b2, fp_w3, fp_b3,
                     pflow);
  hipLaunchKernelGGL(k_greedy, dim3(128), dim3(64), 0, stream,
                     net_c, prio_c, pos_c, en_w1, en_b1, en_w2, en_b2, pflow, g,
                     fl_c, ef_c, total, esent, erecv, nafter);
  hipLaunchKernelGGL(k_write, dim3(4096), dim3(256), 0, stream,
                     fl_c, ef_c, g, row_of, sharing, effm);
}

// Round 6
// 267.548 us; speedup vs baseline: 1.3790x; 1.0253x over previous
//
#include <hip/hip_runtime.h>
#include <math.h>

#define NB 4096
#define NC 128
#define NK 32
#define NE 128

typedef __bf16 bf16x8 __attribute__((ext_vector_type(8)));
typedef float floatx4 __attribute__((ext_vector_type(4)));

__device__ __forceinline__ float sigmoidf_(float x){
  if (x >= 0.f){ float z = expf(-x); return 1.f/(1.f+z); }
  float z = expf(x); return z/(1.f+z);
}
__device__ __forceinline__ float softplusf_(float x){
  // matches jax.nn.softplus = max(x,0) + log1p(exp(-|x|))
  return fmaxf(x, 0.f) + log1pf(expf(-fabsf(x)));
}
__device__ __forceinline__ unsigned int pack_bf16(float a, float b){
  unsigned short ua = __builtin_bit_cast(unsigned short, (__bf16)a);
  unsigned short ub = __builtin_bit_cast(unsigned short, (__bf16)b);
  return (unsigned int)ua | ((unsigned int)ub << 16);
}

// ---------------- prep: transposes (f32), grouping, consts, W2 MFMA-fragment pack ----------------
// blocks 0..79: w1at/w1bt/ps_w1t transposes; 80..95: grouping; 96: consts+total; 97: w2f
// NOTE: first-layer GEMM weights stay f32 — bf16 there compounds through the second
// rounding + greedy allocator and blew the total_shared threshold in R4 (14.0 > 5.48).
__global__ void k_prep_group(const float* __restrict__ fp_w1, const float* __restrict__ ps_w1,
                             const float* __restrict__ fp_b1, const float* __restrict__ fp_w2,
                             const int* __restrict__ assign, const int* __restrict__ hourp,
                             float* __restrict__ w1at, float* __restrict__ w1bt,
                             float* __restrict__ ps_w1t, int* __restrict__ g,
                             int* __restrict__ row_of, float* __restrict__ w1d_c,
                             float* __restrict__ bzc, uint4* __restrict__ w2f,
                             float* __restrict__ total){
  int bid = blockIdx.x;
  int t = threadIdx.x;
  if (bid < 80){
    int idx = bid*256 + t;
    if (idx < 128*128){
      int o = idx >> 7, e = idx & 127;
      w1at[e*128 + o] = fp_w1[o*258 + e];
      w1bt[e*128 + o] = fp_w1[o*258 + 128 + e];
    } else {
      int i2 = idx - 128*128;
      if (i2 < 128*32){
        int e = i2 >> 5, q = i2 & 31;
        ps_w1t[e*32 + q] = ps_w1[q*128 + e];
      }
    }
  } else if (bid < 96){
    __shared__ int hist[NC];
    __shared__ int loc[256];
    int start = (bid - 80)*256;
    for (int c = t; c < NC; c += 256) hist[c] = 0;
    __syncthreads();
    for (int j = t; j < start; j += 256) atomicAdd(&hist[assign[j]], 1);
    int i = start + t;
    int c = assign[i];
    loc[t] = c;
    __syncthreads();
    int r = hist[c];
    for (int j = 0; j < 256; ++j) r += (j < t && loc[j] == c) ? 1 : 0;
    if (r >= NK) r = NK - 1;
    g[c*NK + r] = i;
    row_of[i] = c*NK + r;
  } else if (bid == 96){
    if (t < 128){
      float hour_f = (float)hourp[0] / 24.0f;
      w1d_c[t] = fp_w1[t*258 + 256];
      bzc[t]   = fmaf(hour_f, fp_w1[t*258 + 257], fp_b1[t]);
    }
    if (t == 128) total[0] = 0.f;
  } else {
    // W2 fragments: frag f=(nt*4+ks)*64+lane holds W2[o=nt*16+(lane&15)][ks*32+(lane>>4)*8 + 0..7]
    for (int ff = t; ff < 1024; ff += 256){
      int lane = ff & 63, fi = ff >> 6;
      int nt = fi >> 2, ks = fi & 3;
      int o = nt*16 + (lane & 15);
      int kb = ks*32 + (lane >> 4)*8;
      const float* src = fp_w2 + o*128 + kb;
      uint4 u;
      u.x = pack_bf16(src[0], src[1]);
      u.y = pack_bf16(src[2], src[3]);
      u.z = pack_bf16(src[4], src[5]);
      u.w = pack_bf16(src[6], src[7]);
      w2f[ff] = u;
    }
  }
}

// ---------------- per-building: prio MLP (f32 exact: order feeds greedy), net, pos -------
__global__ void k_prio(const float* __restrict__ emb, const float* __restrict__ gen,
                       const float* __restrict__ cons, const float* __restrict__ pos,
                       const float* __restrict__ ps_w1t, const float* __restrict__ ps_b1,
                       const float* __restrict__ ps_w2, const float* __restrict__ ps_b2,
                       const int* __restrict__ row_of, const int* __restrict__ hourp,
                       float* __restrict__ net_c, float* __restrict__ prio_c,
                       float* __restrict__ pos_c){
  __shared__ float es[8*128];
  __shared__ float ws[128*32];
  int t = threadIdx.x;
  int i0 = blockIdx.x*8;
  for (int idx = t; idx < 8*128; idx += 256) es[idx] = emb[i0*128 + idx];
  for (int idx = t; idx < 128*32; idx += 256) ws[idx] = ps_w1t[idx];
  __syncthreads();
  int bl = t >> 5, q = t & 31;
  int i = i0 + bl;
  float acc = ps_b1[q];
  const float* er = &es[bl*128];
  for (int e = 0; e < 128; ++e) acc = fmaf(er[e], ws[e*32 + q], acc);
  float v = fmaxf(acc, 0.f) * ps_w2[q];
  for (int m = 16; m >= 1; m >>= 1) v += __shfl_xor(v, m, 32);
  if (q == 0){
    int ck = row_of[i];
    prio_c[ck] = sigmoidf_(v + ps_b2[0]);
    int h = hourp[0];
    net_c[ck] = gen[i*24 + h] - cons[i*24 + h];
    pos_c[2*ck]   = pos[2*i];
    pos_c[2*ck+1] = pos[2*i+1];
  }
}

// ---------------- hi/hj = emb @ W1a.T / W1b.T, f32 VALU (precision-critical) ----------------
__global__ void k_hij(const float* __restrict__ emb, const float* __restrict__ w1at,
                      const float* __restrict__ w1bt, const int* __restrict__ row_of,
                      float* __restrict__ hi_c, float* __restrict__ hj_c){
  __shared__ float es[16*132];
  int t = threadIdx.x;
  int i0 = blockIdx.x*16;
  for (int idx = t; idx < 16*128; idx += 256){
    int b = idx >> 7, e = idx & 127;
    es[b*132 + e] = emb[(i0 + b)*128 + e];
  }
  __syncthreads();
  int o = t & 127, half = t >> 7;
  float ai[8], aj[8];
#pragma unroll
  for (int r = 0; r < 8; ++r){ ai[r] = 0.f; aj[r] = 0.f; }
  for (int e = 0; e < 128; e += 4){
    float wa0 = w1at[(e+0)*128 + o], wa1 = w1at[(e+1)*128 + o];
    float wa2 = w1at[(e+2)*128 + o], wa3 = w1at[(e+3)*128 + o];
    float wb0 = w1bt[(e+0)*128 + o], wb1 = w1bt[(e+1)*128 + o];
    float wb2 = w1bt[(e+2)*128 + o], wb3 = w1bt[(e+3)*128 + o];
#pragma unroll
    for (int r = 0; r < 8; ++r){
      float4 ev = *(const float4*)&es[(half*8 + r)*132 + e];
      ai[r] = fmaf(ev.x, wa0, fmaf(ev.y, wa1, fmaf(ev.z, wa2, fmaf(ev.w, wa3, ai[r]))));
      aj[r] = fmaf(ev.x, wb0, fmaf(ev.y, wb1, fmaf(ev.z, wb2, fmaf(ev.w, wb3, aj[r]))));
    }
  }
#pragma unroll
  for (int r = 0; r < 8; ++r){
    int b = i0 + half*8 + r;
    int ck = row_of[b];
    hi_c[ck*128 + o] = ai[r];
    hj_c[ck*128 + o] = aj[r];
  }
}

// ---------------- pflow MLP via MFMA, fully LDS-free ----------------
// wave gw -> (c, i, j0): 16 pairs (i, j0+l16). A-frag built in regs (relu(hi+hj+d*w1d+bz)),
// B-frags = pre-swizzled W2 (16 coalesced dwordx4, L2-hit). Epilogue: relu+b2, dot w3,
// 16-lane reduce, softplus. Single bf16 rounding (same class as R3's passing kernel).
__global__ __launch_bounds__(256) void k_pflow(
    const float* __restrict__ hi_c, const float* __restrict__ hj_c,
    const float* __restrict__ pos_c, const float* __restrict__ w1d_c,
    const float* __restrict__ bzc, const uint4* __restrict__ w2f,
    const float* __restrict__ fp_b2, const float* __restrict__ fp_w3,
    const float* __restrict__ fp_b3, float* __restrict__ pflow){
  int t = threadIdx.x;
  int lane = t & 63, wv = t >> 6;
  int gw = blockIdx.x*4 + wv;            // 0..8191
  int c = gw >> 6;
  int rem = gw & 63;
  int i = rem >> 1, j0 = (rem & 1)*16;
  int l16 = lane & 15, quad = lane >> 4;
  int j = j0 + l16;
  float xi = pos_c[(c*NK + i)*2 + 0], yi = pos_c[(c*NK + i)*2 + 1];
  float xj = pos_c[(c*NK + j)*2 + 0], yj = pos_c[(c*NK + j)*2 + 1];
  float dx = xi - xj, dy = yi - yj;
  float d = sqrtf(fmaf(dx, dx, dy*dy));
  const float4* hi4 = (const float4*)(hi_c + (c*NK + i)*128);
  const float4* hj4 = (const float4*)(hj_c + (c*NK + j)*128);
  const float4* wd4 = (const float4*)w1d_c;
  const float4* bz4 = (const float4*)bzc;
  bf16x8 af[4];
#pragma unroll
  for (int ks = 0; ks < 4; ++ks){
    int q8 = ks*8 + quad*2;
    float4 a0 = hi4[q8], a1 = hi4[q8 + 1];
    float4 b0 = hj4[q8], b1 = hj4[q8 + 1];
    float4 w0 = wd4[q8], w1 = wd4[q8 + 1];
    float4 z0 = bz4[q8], z1 = bz4[q8 + 1];
    float v0 = fmaxf(a0.x + b0.x + fmaf(d, w0.x, z0.x), 0.f);
    float v1 = fmaxf(a0.y + b0.y + fmaf(d, w0.y, z0.y), 0.f);
    float v2 = fmaxf(a0.z + b0.z + fmaf(d, w0.z, z0.z), 0.f);
    float v3 = fmaxf(a0.w + b0.w + fmaf(d, w0.w, z0.w), 0.f);
    float v4 = fmaxf(a1.x + b1.x + fmaf(d, w1.x, z1.x), 0.f);
    float v5 = fmaxf(a1.y + b1.y + fmaf(d, w1.y, z1.y), 0.f);
    float v6 = fmaxf(a1.z + b1.z + fmaf(d, w1.z, z1.z), 0.f);
    float v7 = fmaxf(a1.w + b1.w + fmaf(d, w1.w, z1.w), 0.f);
    uint4 u;
    u.x = pack_bf16(v0, v1);
    u.y = pack_bf16(v2, v3);
    u.z = pack_bf16(v4, v5);
    u.w = pack_bf16(v6, v7);
    af[ks] = __builtin_bit_cast(bf16x8, u);
  }
  bf16x8 bfr[4][4];
#pragma unroll
  for (int nt = 0; nt < 4; ++nt)
#pragma unroll
    for (int ks = 0; ks < 4; ++ks)
      bfr[nt][ks] = __builtin_bit_cast(bf16x8, w2f[(nt*4 + ks)*64 + lane]);
  floatx4 acc[4];
#pragma unroll
  for (int nt = 0; nt < 4; ++nt){
    acc[nt] = (floatx4){0.f, 0.f, 0.f, 0.f};
#pragma unroll
    for (int ks = 0; ks < 4; ++ks)
      acc[nt] = __builtin_amdgcn_mfma_f32_16x16x32_bf16(af[ks], bfr[nt][ks], acc[nt], 0, 0, 0);
  }
  float b2v[4], w3v[4];
#pragma unroll
  for (int nt = 0; nt < 4; ++nt){
    b2v[nt] = fp_b2[nt*16 + l16];
    w3v[nt] = fp_w3[nt*16 + l16];
  }
  float b3 = fp_b3[0];
#pragma unroll
  for (int r = 0; r < 4; ++r){
    float s = 0.f;
#pragma unroll
    for (int nt = 0; nt < 4; ++nt)
      s = fmaf(fmaxf(acc[nt][r] + b2v[nt], 0.f), w3v[nt], s);
#pragma unroll
    for (int m = 8; m >= 1; m >>= 1) s += __shfl_xor(s, m);
    if (l16 == 0)
      pflow[c*1024 + i*32 + j0 + quad*4 + r] = softplusf_(s + b3);
  }
}

// ---------------- greedy allocation: prefix-scan form, eff computed inline ----------------
__global__ __launch_bounds__(64) void k_greedy(
    const float* __restrict__ net_c, const float* __restrict__ prio_c,
    const float* __restrict__ pos_c, const float* __restrict__ en_w1,
    const float* __restrict__ en_b1, const float* __restrict__ en_w2,
    const float* __restrict__ en_b2, const float* __restrict__ pflow,
    const int* __restrict__ g,
    float* __restrict__ fl_c, float* __restrict__ ef_c, float* __restrict__ total,
    float* __restrict__ esent, float* __restrict__ erecv, float* __restrict__ nafter){
  __shared__ float pf_s[1024];
  __shared__ float ef_s[1024];
  __shared__ float fl_s[1024];
  __shared__ float efm_s[1024];
  __shared__ float px[32], py[32];
  __shared__ int order_s[32];
  __shared__ int gl[32];
  int t = threadIdx.x;
  int tl = t & 31;
  int c = blockIdx.x;
  for (int e = t; e < 1024; e += 64) pf_s[e] = pflow[c*1024 + e];
  if (t < 32){
    float2 p2 = ((const float2*)pos_c)[c*NK + t];
    px[t] = p2.x; py[t] = p2.y;
    gl[t] = g[c*NK + t];
  }
  __syncthreads();
  for (int e = t; e < 1024; e += 64){
    int ii = e >> 5, jj = e & 31;
    float dx = px[ii] - px[jj], dy = py[ii] - py[jj];
    float d = sqrtf(fmaf(dx, dx, dy*dy));
    float ds = d * (1.0f/1000.0f);
    float acc = en_b2[0];
#pragma unroll
    for (int q = 0; q < 16; ++q)
      acc = fmaf(fmaxf(fmaf(ds, en_w1[q], en_b1[q]), 0.f), en_w2[q], acc);
    ef_s[e] = 0.85f + 0.13f*sigmoidf_(acc);
  }
  float p = (t < 32) ? prio_c[c*NK + t] : -1e30f;
  int rank = 0;
  for (int k = 0; k < 32; ++k){
    float pk = __shfl(p, k, 32);
    rank += ((pk > p) || (pk == p && k < tl)) ? 1 : 0;
  }
  if (t < 32) order_s[rank] = t;
  __syncthreads();
  int b = order_s[tl];
  float net0 = net_c[c*NK + b];
  float dnet = net0;
  float recv = 0.f;
  float ctotal = 0.f;
  for (int i = 0; i < 32; ++i){
    int a = order_s[i];
    float av0 = fmaxf(__shfl(net0, i, 32), 0.f);
    float pf = pf_s[a*32 + b];
    float ef = ef_s[a*32 + b];
    float needed = -dnet;
    float m = (needed > 0.f) ? fminf(needed, pf) : 0.f;
    float s = m;
#pragma unroll
    for (int dd = 1; dd < 32; dd <<= 1){
      float u = __shfl_up(s, dd, 32);
      if (tl >= dd) s += u;
    }
    float Se = __shfl_up(s, 1, 32);
    if (tl == 0) Se = 0.f;
    float rprev = fmaxf(av0 - Se, 0.f);
    int act = (rprev > 0.f) && (needed > 0.f);
    float f = fminf(m, rprev);
    dnet = fmaf(f, ef, dnet);
    recv = fmaf(f, ef, recv);
    if (t < 32){
      fl_s[a*32 + b]  = f;
      efm_s[a*32 + b] = act ? ef : 1.0f;
    }
    float rs = f;
    for (int mm = 16; mm >= 1; mm >>= 1) rs += __shfl_xor(rs, mm, 32);
    if (t == 0){ esent[gl[a]] = rs; ctotal += rs; }
  }
  if (t < 32){
    nafter[gl[b]] = dnet;
    erecv[gl[b]]  = recv;
  }
  if (t == 0) atomicAdd(total, ctotal);
  __syncthreads();
  for (int e = t; e < 1024; e += 64){
    fl_c[c*1024 + e] = fl_s[e];
    ef_c[c*1024 + e] = efm_s[e];
  }
}

// ---------------- stream N x N outputs: build each row in LDS, write once ----------------
__global__ __launch_bounds__(256) void k_write(
    const float* __restrict__ fl_c, const float* __restrict__ ef_c,
    const int* __restrict__ g, const int* __restrict__ row_of,
    float* __restrict__ sharing, float* __restrict__ effm){
  __shared__ float rowS[4096];
  __shared__ float rowE[4096];
  __shared__ int   cols[32];
  __shared__ float vals[32];
  __shared__ float vale[32];
  int t = threadIdx.x;
  int r = blockIdx.x;
  int ra = row_of[r];
  int c = ra >> 5, a = ra & 31;
  if (t < 32){
    cols[t] = g[c*NK + t];
    vals[t] = fl_c[c*1024 + a*32 + t];
    vale[t] = ef_c[c*1024 + a*32 + t];
  }
  float4 z4 = make_float4(0.f, 0.f, 0.f, 0.f);
  float4 o4 = make_float4(1.f, 1.f, 1.f, 1.f);
  float4* s4 = (float4*)rowS;
  float4* e4 = (float4*)rowE;
#pragma unroll
  for (int q = 0; q < 4; ++q){ s4[t + 256*q] = z4; e4[t + 256*q] = o4; }
  __syncthreads();
  if (t < 32){ rowS[cols[t]] = vals[t]; rowE[cols[t]] = vale[t]; }
  __syncthreads();
  float4* gs = (float4*)(sharing + (long)r*NB);
  float4* ge = (float4*)(effm    + (long)r*NB);
#pragma unroll
  for (int q = 0; q < 4; ++q){ gs[t + 256*q] = s4[t + 256*q]; ge[t + 256*q] = e4[t + 256*q]; }
}

extern "C" void kernel_launch(void* const* d_in, const int* in_sizes, int n_in,
                              void* d_out, int out_size, void* d_ws, size_t ws_size,
                              hipStream_t stream){
  (void)in_sizes; (void)n_in; (void)out_size; (void)ws_size;
  const float* emb   = (const float*)d_in[0];
  const float* gen   = (const float*)d_in[1];
  const float* cons  = (const float*)d_in[2];
  const float* pos   = (const float*)d_in[3];
  const float* fp_w1 = (const float*)d_in[4];
  const float* fp_b1 = (const float*)d_in[5];
  const float* fp_w2 = (const float*)d_in[6];
  const float* fp_b2 = (const float*)d_in[7];
  const float* fp_w3 = (const float*)d_in[8];
  const float* fp_b3 = (const float*)d_in[9];
  const float* en_w1 = (const float*)d_in[10];
  const float* en_b1 = (const float*)d_in[11];
  const float* en_w2 = (const float*)d_in[12];
  const float* en_b2 = (const float*)d_in[13];
  const float* ps_w1 = (const float*)d_in[14];
  const float* ps_b1 = (const float*)d_in[15];
  const float* ps_w2 = (const float*)d_in[16];
  const float* ps_b2 = (const float*)d_in[17];
  const int*   assign = (const int*)d_in[18];
  const int*   hourp  = (const int*)d_in[20];

  // Workspace map (NO OVERLAPS — R5 failed because w2f@246784+16KB ran into hi_c@262144):
  char* ws = (char*)d_ws;
  float* w1at   = (float*)(ws + 0);           // 64 KB   [0,      65536)
  float* w1bt   = (float*)(ws + 65536);       // 64 KB   [65536,  131072)
  float* ps_w1t = (float*)(ws + 131072);      // 16 KB   [131072, 147456)
  int*   g      = (int*)  (ws + 147456);      // 16 KB   [147456, 163840)
  int*   row_of = (int*)  (ws + 163840);      // 16 KB   [163840, 180224)
  float* net_c  = (float*)(ws + 180224);      // 16 KB   [180224, 196608)
  float* prio_c = (float*)(ws + 196608);      // 16 KB   [196608, 212992)
  float* pos_c  = (float*)(ws + 212992);      // 32 KB   [212992, 245760)
  float* w1d_c  = (float*)(ws + 245760);      // 512 B   [245760, 246272)
  float* bzc    = (float*)(ws + 246272);      // 512 B   [246272, 246784)
  float* hi_c   = (float*)(ws + 262144);      // 2 MB    [262144, 2359296)
  float* hj_c   = (float*)(ws + 2359296);     // 2 MB    [2359296, 4456448)
  float* pflow  = (float*)(ws + 4456448);     // 512 KB  [4456448, 4980736)
  float* fl_c   = (float*)(ws + 4980736);     // 512 KB  [4980736, 5505024)
  float* ef_c   = (float*)(ws + 5505024);     // 512 KB  [5505024, 6029312)
  uint4* w2f    = (uint4*)(ws + 6029312);     // 16 KB   [6029312, 6045696)  (R3's proven slot)

  float* sharing = (float*)d_out;
  float* effm    = sharing + (long)NB*NB;
  float* total   = effm + (long)NB*NB;
  float* esent   = total + 1;
  float* erecv   = esent + NB;
  float* nafter  = erecv + NB;

  hipLaunchKernelGGL(k_prep_group, dim3(98), dim3(256), 0, stream,
                     fp_w1, ps_w1, fp_b1, fp_w2, assign, hourp,
                     w1at, w1bt, ps_w1t, g, row_of, w1d_c, bzc, w2f, total);
  hipLaunchKernelGGL(k_prio, dim3(512), dim3(256), 0, stream,
                     emb, gen, cons, pos, ps_w1t, ps_b1, ps_w2, ps_b2,
                     row_of, hourp, net_c, prio_c, pos_c);
  hipLaunchKernelGGL(k_hij, dim3(256), dim3(256), 0, stream,
                     emb, w1at, w1bt, row_of, hi_c, hj_c);
  hipLaunchKernelGGL(k_pflow, dim3(2048), dim3(256), 0, stream,
                     hi_c, hj_c, pos_c, w1d_c, bzc, w2f, fp_b2, fp_w3, fp_b3,
                     pflow);
  hipLaunchKernelGGL(k_greedy, dim3(128), dim3(64), 0, stream,
                     net_c, prio_c, pos_c, en_w1, en_b1, en_w2, en_b2, pflow, g,
                     fl_c, ef_c, total, esent, erecv, nafter);
  hipLaunchKernelGGL(k_write, dim3(4096), dim3(256), 0, stream,
                     fl_c, ef_c, g, row_of, sharing, effm);
}